// Round 2
// baseline (786.344 us; speedup 1.0000x reference)
//
#include <hip/hip_runtime.h>

#define B_   2
#define S_   2048
#define E_   2048
#define QKV_ 3072
#define NH   16
#define NKV  4
#define HD   128

typedef __attribute__((ext_vector_type(8))) short bf16x8;
typedef __attribute__((ext_vector_type(4))) float f32x4;
typedef unsigned short u16;
typedef unsigned int   u32;

__device__ __forceinline__ float bf2f(u16 u) {
  union { u32 i; float f; } v; v.i = ((u32)u) << 16; return v.f;
}
__device__ __forceinline__ u16 f2bf(float f) {
  union { float f; u32 u; } v; v.f = f;
  return (u16)((v.u + 0x7FFFu + ((v.u >> 16) & 1u)) >> 16);
}
__device__ __forceinline__ void load_lds16(const u16* g, u16* l) {
  __builtin_amdgcn_global_load_lds((const __attribute__((address_space(1))) void*)g,
                                   (__attribute__((address_space(3))) void*)l, 16, 0, 0);
}

// ---------------- fp32 -> bf16 bulk convert (n multiple of 4) ----------------
__global__ __launch_bounds__(256) void f2b_conv(const float* __restrict__ in,
                                                u16* __restrict__ out, int n4) {
  const int i = blockIdx.x * 256 + threadIdx.x;
  if (i >= n4) return;
  const float4 v = ((const float4*)in)[i];
  ushort4 o;
  o.x = f2bf(v.x); o.y = f2bf(v.y); o.z = f2bf(v.z); o.w = f2bf(v.w);
  ((ushort4*)out)[i] = o;
}

// ---------------- GEMM: C[M,N] = A[M,K] * B[N,K]^T + bias[N] ----------------
// A, B bf16 K-major. 128x128 tile, 256 thr / 4 waves, BK=32 (m97 structure).
// bias fp32. OUT_BF16: 1 -> bf16 C, 0 -> fp32 C.
template <int OUT_BF16>
__global__ __launch_bounds__(256) void gemm_bt(const u16* __restrict__ A,
                                               const u16* __restrict__ Bm,
                                               const float* __restrict__ bias,
                                               void* __restrict__ C,
                                               int M, int N, int K) {
  __shared__ u16 As[128 * 32];
  __shared__ u16 Bs[128 * 32];
  const int tid = threadIdx.x;
  const int wave = tid >> 6, lane = tid & 63;
  const int m0 = blockIdx.y * 128, n0 = blockIdx.x * 128;
  const int wm = (wave & 1) * 64, wn = (wave >> 1) * 64;
  const int L15 = lane & 15, Lq = lane >> 4;
  const int lrow = lane >> 2, lcol = (lane & 3) * 8;

  f32x4 acc[4][4] = {};

  for (int k0 = 0; k0 < K; k0 += 32) {
#pragma unroll
    for (int c = 0; c < 2; ++c) {
      const int chunk = c * 4 + wave;
      const int row = chunk * 16 + lrow;
      load_lds16(A  + (size_t)(m0 + row) * K + k0 + lcol, &As[chunk * 512 + lane * 8]);
      load_lds16(Bm + (size_t)(n0 + row) * K + k0 + lcol, &Bs[chunk * 512 + lane * 8]);
    }
    __syncthreads();
    bf16x8 af[4], bfr[4];
#pragma unroll
    for (int t = 0; t < 4; ++t) {
      af[t]  = *(const bf16x8*)&As[(wm + t * 16 + L15) * 32 + Lq * 8];
      bfr[t] = *(const bf16x8*)&Bs[(wn + t * 16 + L15) * 32 + Lq * 8];
    }
#pragma unroll
    for (int mt = 0; mt < 4; ++mt)
#pragma unroll
      for (int nt = 0; nt < 4; ++nt)
        acc[mt][nt] = __builtin_amdgcn_mfma_f32_16x16x32_bf16(af[mt], bfr[nt], acc[mt][nt], 0, 0, 0);
    __syncthreads();
  }

#pragma unroll
  for (int nt = 0; nt < 4; ++nt) {
    const int col = n0 + wn + nt * 16 + L15;
    const float bv = bias[col];
#pragma unroll
    for (int mt = 0; mt < 4; ++mt) {
#pragma unroll
      for (int r = 0; r < 4; ++r) {
        const int row = m0 + wm + mt * 16 + Lq * 4 + r;
        const float v = acc[mt][nt][r] + bv;
        if (OUT_BF16) ((u16*)C)[(size_t)row * N + col] = f2bf(v);
        else          ((float*)C)[(size_t)row * N + col] = v;
      }
    }
  }
}

// ------------- depthwise causal conv(4) + bias + RoPE + split/layout -------------
// qkv bf16 (B,S,QKV) -> q bf16 (B,NH,S,HD) [pre-scaled by 1/sqrt(HD)],
//                       k bf16 (B,NKV,S,HD), v^T bf16 (B,NKV,HD,S)
__global__ __launch_bounds__(256) void conv_rope(const u16* __restrict__ qkv,
                                                 const float* __restrict__ cw,
                                                 const float* __restrict__ cb,
                                                 u16* __restrict__ qo,
                                                 u16* __restrict__ ko,
                                                 u16* __restrict__ vo) {
  const int bs = blockIdx.x;
  const int b = bs >> 11, s = bs & 2047;
  const int tid = threadIdx.x;

  auto conv1 = [&](int f) -> float {
    float a = cb[f];
#pragma unroll
    for (int d = 0; d < 4; ++d) {
      const int t = s - 3 + d;
      if (t >= 0) a += cw[f * 4 + d] * bf2f(qkv[((size_t)b * S_ + t) * QKV_ + f]);
    }
    return a;
  };

  // q and k rotary pairs: (NH+NKV)*64 = 1280 pairs
  for (int p = tid; p < (NH + NKV) * 64; p += 256) {
    int f1, i; u16* outp; float scale;
    if (p < NH * 64) {
      const int h = p >> 6; i = p & 63;
      f1 = h * HD + i;
      outp = qo + ((size_t)(b * NH + h) * S_ + s) * HD;
      scale = 0.08838834764831845f;  // 1/sqrt(128)
    } else {
      const int pk = p - NH * 64;
      const int h = pk >> 6; i = pk & 63;
      f1 = NH * HD + h * HD + i;
      outp = ko + ((size_t)(b * NKV + h) * S_ + s) * HD;
      scale = 1.0f;
    }
    const float x1 = conv1(f1);
    const float x2 = conv1(f1 + 64);
    const float invf = powf(10000.0f, -(float)i * (1.0f / 64.0f));
    const float ang = (float)s * invf;
    float sn, cs;
    sincosf(ang, &sn, &cs);
    outp[i]      = f2bf((x1 * cs - x2 * sn) * scale);
    outp[i + 64] = f2bf((x2 * cs + x1 * sn) * scale);
  }
  // v: NKV*HD = 512 features, stored transposed (d-major)
  for (int p = tid; p < NKV * HD; p += 256) {
    const int f = (NH + NKV) * HD + p;
    const int h = p >> 7, d = p & 127;
    vo[((size_t)(b * NKV + h) * HD + d) * S_ + s] = f2bf(conv1(f));
  }
}

// ------------------------- flash attention (causal, GQA) -------------------------
// grid (S/64, B*NH); 4 waves x 16 q-rows. ctx bf16 (B,S,NH*HD)
__global__ __launch_bounds__(256) void attn(const u16* __restrict__ q,
                                            const u16* __restrict__ k,
                                            const u16* __restrict__ v,
                                            u16* __restrict__ ctx) {
  // per-wave P tile; stride 80 u16 = 160 B keeps ds_read_b128 16B-aligned
  __shared__ u16 P[4][16 * 80];
  const int tid = threadIdx.x, wave = tid >> 6, lane = tid & 63;
  const int L15 = lane & 15, Lq = lane >> 4;
  const int qt = blockIdx.x, bh = blockIdx.y;
  const int b = bh >> 4, h = bh & 15, hk = h >> 2;
  const int q0 = qt * 64;
  const int qrow = q0 + wave * 16 + L15;

  const u16* qp = q + ((size_t)bh * S_ + qrow) * HD + Lq * 8;
  bf16x8 qf[4];
#pragma unroll
  for (int c = 0; c < 4; ++c) qf[c] = *(const bf16x8*)(qp + c * 32);

  f32x4 acc[8] = {};
  float m_i[4], l_i[4];
#pragma unroll
  for (int r = 0; r < 4; ++r) { m_i[r] = -1e30f; l_i[r] = 0.f; }

  const u16* kb = k + (size_t)(b * NKV + hk) * S_ * HD;
  const u16* vb = v + (size_t)(b * NKV + hk) * HD * S_;

  for (int kt = 0; kt <= qt; ++kt) {
    const int k0 = kt * 64;
    f32x4 sc[4];
#pragma unroll
    for (int nt = 0; nt < 4; ++nt) {
      f32x4 s = {};
      const u16* kr = kb + (size_t)(k0 + nt * 16 + L15) * HD + Lq * 8;
#pragma unroll
      for (int c = 0; c < 4; ++c) {
        const bf16x8 kf = *(const bf16x8*)(kr + c * 32);
        s = __builtin_amdgcn_mfma_f32_16x16x32_bf16(qf[c], kf, s, 0, 0, 0);
      }
      sc[nt] = s;
    }
    if (kt == qt) {  // only the diagonal tile needs causal masking
#pragma unroll
      for (int nt = 0; nt < 4; ++nt) {
        const int col = k0 + nt * 16 + L15;
#pragma unroll
        for (int r = 0; r < 4; ++r) {
          const int row = q0 + wave * 16 + Lq * 4 + r;
          if (col > row) sc[nt][r] = -1e30f;
        }
      }
    }
    // online softmax: C-layout row m = Lq*4+r; butterfly over the 16 cols
    float mloc[4];
#pragma unroll
    for (int r = 0; r < 4; ++r) {
      mloc[r] = fmaxf(fmaxf(sc[0][r], sc[1][r]), fmaxf(sc[2][r], sc[3][r]));
      mloc[r] = fmaxf(mloc[r], __shfl_xor(mloc[r], 1));
      mloc[r] = fmaxf(mloc[r], __shfl_xor(mloc[r], 2));
      mloc[r] = fmaxf(mloc[r], __shfl_xor(mloc[r], 4));
      mloc[r] = fmaxf(mloc[r], __shfl_xor(mloc[r], 8));
    }
    float mnew[4], alpha[4], rsum[4];
#pragma unroll
    for (int r = 0; r < 4; ++r) {
      mnew[r] = fmaxf(m_i[r], mloc[r]);
      alpha[r] = __expf(m_i[r] - mnew[r]);
      m_i[r] = mnew[r];
      rsum[r] = 0.f;
    }
#pragma unroll
    for (int nt = 0; nt < 4; ++nt)
#pragma unroll
      for (int r = 0; r < 4; ++r) {
        const float pv = __expf(sc[nt][r] - mnew[r]);
        const u16 pb = f2bf(pv);
        P[wave][(Lq * 4 + r) * 80 + nt * 16 + L15] = pb;
        rsum[r] += bf2f(pb);  // keep numerator/denominator consistent
      }
#pragma unroll
    for (int r = 0; r < 4; ++r) {
      rsum[r] += __shfl_xor(rsum[r], 1);
      rsum[r] += __shfl_xor(rsum[r], 2);
      rsum[r] += __shfl_xor(rsum[r], 4);
      rsum[r] += __shfl_xor(rsum[r], 8);
      l_i[r] = l_i[r] * alpha[r] + rsum[r];
    }
    // C-layout -> A-layout via per-wave LDS slice: intra-wave dependence only,
    // lgkmcnt ordering handles it (no barrier needed).
    bf16x8 pa[2];
#pragma unroll
    for (int kc = 0; kc < 2; ++kc)
      pa[kc] = *(const bf16x8*)&P[wave][L15 * 80 + kc * 32 + Lq * 8];
#pragma unroll
    for (int dt = 0; dt < 8; ++dt)
#pragma unroll
      for (int r = 0; r < 4; ++r) acc[dt][r] *= alpha[r];
#pragma unroll
    for (int dt = 0; dt < 8; ++dt) {
#pragma unroll
      for (int kc = 0; kc < 2; ++kc) {
        const u16* vr = vb + (size_t)(dt * 16 + L15) * S_ + k0 + kc * 32 + Lq * 8;
        const bf16x8 vf = *(const bf16x8*)vr;
        acc[dt] = __builtin_amdgcn_mfma_f32_16x16x32_bf16(pa[kc], vf, acc[dt], 0, 0, 0);
      }
    }
  }
  float inv[4];
#pragma unroll
  for (int r = 0; r < 4; ++r) inv[r] = 1.f / l_i[r];
  u16* cp = ctx + ((size_t)b * S_ + q0 + wave * 16) * (NH * HD) + h * HD;
#pragma unroll
  for (int dt = 0; dt < 8; ++dt)
#pragma unroll
    for (int r = 0; r < 4; ++r)
      cp[(size_t)(Lq * 4 + r) * (NH * HD) + dt * 16 + L15] = f2bf(acc[dt][r] * inv[r]);
}

extern "C" void kernel_launch(void* const* d_in, const int* in_sizes, int n_in,
                              void* d_out, int out_size, void* d_ws, size_t ws_size,
                              hipStream_t stream) {
  const float* x     = (const float*)d_in[0];
  const float* W_in  = (const float*)d_in[1];
  const float* b_in  = (const float*)d_in[2];
  const float* cw    = (const float*)d_in[3];
  const float* cb    = (const float*)d_in[4];
  const float* W_out = (const float*)d_in[5];
  const float* b_out = (const float*)d_in[6];

  char* ws = (char*)d_ws;
  u16* xb   = (u16*)(ws);                    // 8388608 el  = 16777216 B
  u16* wib  = (u16*)(ws + 16777216);         // 6291456 el  = 12582912 B
  u16* wob  = (u16*)(ws + 29360128);         // 4194304 el  =  8388608 B
  u16* qkv  = (u16*)(ws + 37748736);         // 12582912 el = 25165824 B
  u16* q_ws = (u16*)(ws + 62914560);         // 16777216 B
  u16* k_ws = (u16*)(ws + 79691776);         //  4194304 B
  u16* vt_ws= (u16*)(ws + 83886080);         //  4194304 B
  u16* ctx  = xb;                            // alias: xb dead after gemm1

  const int nx = B_ * S_ * E_ / 4, nwi = QKV_ * E_ / 4, nwo = E_ * NH * HD / 4;
  f2b_conv<<<dim3((nx  + 255) / 256), 256, 0, stream>>>(x,     xb,  nx);
  f2b_conv<<<dim3((nwi + 255) / 256), 256, 0, stream>>>(W_in,  wib, nwi);
  f2b_conv<<<dim3((nwo + 255) / 256), 256, 0, stream>>>(W_out, wob, nwo);

  gemm_bt<1><<<dim3(QKV_ / 128, (B_ * S_) / 128), 256, 0, stream>>>(
      xb, wib, b_in, (void*)qkv, B_ * S_, QKV_, E_);
  conv_rope<<<dim3(B_ * S_), 256, 0, stream>>>(qkv, cw, cb, q_ws, k_ws, vt_ws);
  attn<<<dim3(S_ / 64, B_ * NH), 256, 0, stream>>>(q_ws, k_ws, vt_ws, ctx);
  gemm_bt<0><<<dim3(E_ / 128, (B_ * S_) / 128), 256, 0, stream>>>(
      ctx, wob, b_out, d_out, B_ * S_, E_, NH * HD);
}

// Round 3
// 483.165 us; speedup vs baseline: 1.6275x; 1.6275x over previous
//
#include <hip/hip_runtime.h>

#define B_   2
#define S_   2048
#define E_   2048
#define QKV_ 3072
#define NH   16
#define NKV  4
#define HD   128

typedef __attribute__((ext_vector_type(8))) short bf16x8;
typedef __attribute__((ext_vector_type(4))) float f32x4;
typedef unsigned short u16;
typedef unsigned int   u32;

__device__ __forceinline__ float bf2f(u16 u) {
  union { u32 i; float f; } v; v.i = ((u32)u) << 16; return v.f;
}
__device__ __forceinline__ u16 f2bf(float f) {
  union { float f; u32 u; } v; v.f = f;
  return (u16)((v.u + 0x7FFFu + ((v.u >> 16) & 1u)) >> 16);
}
__device__ __forceinline__ void load_lds16(const u16* g, u16* l) {
  __builtin_amdgcn_global_load_lds((const __attribute__((address_space(1))) void*)g,
                                   (__attribute__((address_space(3))) void*)l, 16, 0, 0);
}

// ---------------- fp32 -> bf16 bulk convert (n multiple of 4) ----------------
__global__ __launch_bounds__(256) void f2b_conv(const float* __restrict__ in,
                                                u16* __restrict__ out, int n4) {
  const int i = blockIdx.x * 256 + threadIdx.x;
  if (i >= n4) return;
  const float4 v = ((const float4*)in)[i];
  ushort4 o;
  o.x = f2bf(v.x); o.y = f2bf(v.y); o.z = f2bf(v.z); o.w = f2bf(v.w);
  ((ushort4*)out)[i] = o;
}

// ---------------- rope table: cos/sin[s*64+i] ----------------
__global__ __launch_bounds__(256) void rope_tab(float* __restrict__ c,
                                                float* __restrict__ s) {
  const int idx = blockIdx.x * 256 + threadIdx.x;  // 2048*64
  const int t = idx >> 6, i = idx & 63;
  const float invf = powf(10000.0f, -(float)i * (1.0f / 64.0f));
  float sn, cs;
  sincosf((float)t * invf, &sn, &cs);
  c[idx] = cs; s[idx] = sn;
}

// ---------------- GEMM: C[M,N] = A[M,K] * B[N,K]^T + bias[N] ----------------
template <int OUT_BF16>
__global__ __launch_bounds__(256) void gemm_bt(const u16* __restrict__ A,
                                               const u16* __restrict__ Bm,
                                               const float* __restrict__ bias,
                                               void* __restrict__ C,
                                               int M, int N, int K) {
  __shared__ u16 As[128 * 32];
  __shared__ u16 Bs[128 * 32];
  const int tid = threadIdx.x;
  const int wave = tid >> 6, lane = tid & 63;
  const int m0 = blockIdx.y * 128, n0 = blockIdx.x * 128;
  const int wm = (wave & 1) * 64, wn = (wave >> 1) * 64;
  const int L15 = lane & 15, Lq = lane >> 4;
  const int lrow = lane >> 2, lcol = (lane & 3) * 8;

  f32x4 acc[4][4] = {};

  for (int k0 = 0; k0 < K; k0 += 32) {
#pragma unroll
    for (int c = 0; c < 2; ++c) {
      const int chunk = c * 4 + wave;
      const int row = chunk * 16 + lrow;
      load_lds16(A  + (size_t)(m0 + row) * K + k0 + lcol, &As[chunk * 512 + lane * 8]);
      load_lds16(Bm + (size_t)(n0 + row) * K + k0 + lcol, &Bs[chunk * 512 + lane * 8]);
    }
    __syncthreads();
    bf16x8 af[4], bfr[4];
#pragma unroll
    for (int t = 0; t < 4; ++t) {
      af[t]  = *(const bf16x8*)&As[(wm + t * 16 + L15) * 32 + Lq * 8];
      bfr[t] = *(const bf16x8*)&Bs[(wn + t * 16 + L15) * 32 + Lq * 8];
    }
#pragma unroll
    for (int mt = 0; mt < 4; ++mt)
#pragma unroll
      for (int nt = 0; nt < 4; ++nt)
        acc[mt][nt] = __builtin_amdgcn_mfma_f32_16x16x32_bf16(af[mt], bfr[nt], acc[mt][nt], 0, 0, 0);
    __syncthreads();
  }

#pragma unroll
  for (int nt = 0; nt < 4; ++nt) {
    const int col = n0 + wn + nt * 16 + L15;
    const float bv = bias[col];
#pragma unroll
    for (int mt = 0; mt < 4; ++mt) {
#pragma unroll
      for (int r = 0; r < 4; ++r) {
        const int row = m0 + wm + mt * 16 + Lq * 4 + r;
        const float v = acc[mt][nt][r] + bv;
        if (OUT_BF16) ((u16*)C)[(size_t)row * N + col] = f2bf(v);
        else          ((float*)C)[(size_t)row * N + col] = v;
      }
    }
  }
}

// ------------- depthwise causal conv(4) + bias + RoPE + split/layout -------------
__global__ __launch_bounds__(256) void conv_rope(const u16* __restrict__ qkv,
                                                 const float* __restrict__ cw,
                                                 const float* __restrict__ cb,
                                                 const float* __restrict__ ct,
                                                 const float* __restrict__ st,
                                                 u16* __restrict__ qo,
                                                 u16* __restrict__ ko,
                                                 u16* __restrict__ vo) {
  const int bs = blockIdx.x;
  const int b = bs >> 11, s = bs & 2047;
  const int tid = threadIdx.x;

  auto conv1 = [&](int f) -> float {
    float a = cb[f];
#pragma unroll
    for (int d = 0; d < 4; ++d) {
      const int t = s - 3 + d;
      if (t >= 0) a += cw[f * 4 + d] * bf2f(qkv[((size_t)b * S_ + t) * QKV_ + f]);
    }
    return a;
  };

  for (int p = tid; p < (NH + NKV) * 64; p += 256) {
    int f1, i; u16* outp; float scale;
    if (p < NH * 64) {
      const int h = p >> 6; i = p & 63;
      f1 = h * HD + i;
      outp = qo + ((size_t)(b * NH + h) * S_ + s) * HD;
      scale = 0.08838834764831845f;  // 1/sqrt(128)
    } else {
      const int pk = p - NH * 64;
      const int h = pk >> 6; i = pk & 63;
      f1 = NH * HD + h * HD + i;
      outp = ko + ((size_t)(b * NKV + h) * S_ + s) * HD;
      scale = 1.0f;
    }
    const float x1 = conv1(f1);
    const float x2 = conv1(f1 + 64);
    const float cs = ct[s * 64 + i], sn = st[s * 64 + i];
    outp[i]      = f2bf((x1 * cs - x2 * sn) * scale);
    outp[i + 64] = f2bf((x2 * cs + x1 * sn) * scale);
  }
  for (int p = tid; p < NKV * HD; p += 256) {
    const int f = (NH + NKV) * HD + p;
    const int h = p >> 7, d = p & 127;
    vo[((size_t)(b * NKV + h) * HD + d) * S_ + s] = f2bf(conv1(f));
  }
}

// ------------------------- flash attention (causal, GQA) -------------------------
// grid (32, B*NH); block = 4 waves over one 64-row q-tile.
// K-tile 64x128 and V^T-tile 128x64 staged in LDS (shared by all 4 waves),
// next tile prefetched into registers while computing the current one.
#define KST 136  // K LDS row stride (u16): 272B, 16B-aligned, conflict-free
#define VST 72   // V LDS row stride (u16): 144B
#define PST 72   // P LDS row stride (u16)
__global__ __launch_bounds__(256) void attn(const u16* __restrict__ q,
                                            const u16* __restrict__ k,
                                            const u16* __restrict__ v,
                                            u16* __restrict__ ctx) {
  __shared__ u16 Ks[64 * KST];
  __shared__ u16 Vs[128 * VST];
  __shared__ u16 P[4][16 * PST];
  const int tid = threadIdx.x, wave = tid >> 6, lane = tid & 63;
  const int L15 = lane & 15, Lq = lane >> 4;
  const int qt = gridDim.x - 1 - blockIdx.x;  // longest blocks dispatch first
  const int bh = blockIdx.y;
  const int b = bh >> 4, h = bh & 15, hk = h >> 2;
  const int q0 = qt * 64;
  const int qrow = q0 + wave * 16 + L15;

  const u16* qp = q + ((size_t)bh * S_ + qrow) * HD + Lq * 8;
  bf16x8 qf[4];
#pragma unroll
  for (int c = 0; c < 4; ++c) qf[c] = *(const bf16x8*)(qp + c * 32);

  f32x4 acc[8] = {};
  float m_i[4], l_i[4];
#pragma unroll
  for (int r = 0; r < 4; ++r) { m_i[r] = -1e30f; l_i[r] = 0.f; }

  const u16* kb = k + (size_t)(b * NKV + hk) * S_ * HD;
  const u16* vb = v + (size_t)(b * NKV + hk) * HD * S_;

  // staging coords: K flat idx -> (row 0..63, 16B-chunk 0..15); V -> (row 0..127, chunk 0..7)
  const int kr0 = tid >> 4, kc0 = (tid & 15) * 8;   // +j*16 rows
  const int vr0 = tid >> 3, vc0 = (tid & 7) * 8;    // +j*32 rows

  bf16x8 kpre[4], vpre[4];
#pragma unroll
  for (int j = 0; j < 4; ++j) {
    kpre[j] = *(const bf16x8*)(kb + (size_t)(kr0 + j * 16) * HD + kc0);
    vpre[j] = *(const bf16x8*)(vb + (size_t)(vr0 + j * 32) * S_ + vc0);
  }
#pragma unroll
  for (int j = 0; j < 4; ++j) {
    *(bf16x8*)&Ks[(kr0 + j * 16) * KST + kc0] = kpre[j];
    *(bf16x8*)&Vs[(vr0 + j * 32) * VST + vc0] = vpre[j];
  }
  __syncthreads();

  for (int kt = 0; kt <= qt; ++kt) {
    const int k0 = kt * 64;
    if (kt < qt) {  // prefetch next tile into registers (overlaps compute)
      const int kn = k0 + 64;
#pragma unroll
      for (int j = 0; j < 4; ++j) {
        kpre[j] = *(const bf16x8*)(kb + (size_t)(kn + kr0 + j * 16) * HD + kc0);
        vpre[j] = *(const bf16x8*)(vb + (size_t)(vr0 + j * 32) * S_ + kn + vc0);
      }
    }
    // ---- QK^T from LDS ----
    f32x4 sc[4];
#pragma unroll
    for (int nt = 0; nt < 4; ++nt) {
      f32x4 s = {};
#pragma unroll
      for (int c = 0; c < 4; ++c) {
        const bf16x8 kf = *(const bf16x8*)&Ks[(nt * 16 + L15) * KST + c * 32 + Lq * 8];
        s = __builtin_amdgcn_mfma_f32_16x16x32_bf16(qf[c], kf, s, 0, 0, 0);
      }
      sc[nt] = s;
    }
    if (kt == qt) {
#pragma unroll
      for (int nt = 0; nt < 4; ++nt) {
        const int col = nt * 16 + L15;
#pragma unroll
        for (int r = 0; r < 4; ++r) {
          const int row = wave * 16 + Lq * 4 + r;
          if (col > row) sc[nt][r] = -1e30f;
        }
      }
    }
    // ---- online softmax (C-layout rows = Lq*4+r, 16 cols per lane-set) ----
    float mloc[4];
#pragma unroll
    for (int r = 0; r < 4; ++r) {
      mloc[r] = fmaxf(fmaxf(sc[0][r], sc[1][r]), fmaxf(sc[2][r], sc[3][r]));
      mloc[r] = fmaxf(mloc[r], __shfl_xor(mloc[r], 1));
      mloc[r] = fmaxf(mloc[r], __shfl_xor(mloc[r], 2));
      mloc[r] = fmaxf(mloc[r], __shfl_xor(mloc[r], 4));
      mloc[r] = fmaxf(mloc[r], __shfl_xor(mloc[r], 8));
    }
    float mnew[4], alpha[4], rsum[4];
#pragma unroll
    for (int r = 0; r < 4; ++r) {
      mnew[r] = fmaxf(m_i[r], mloc[r]);
      alpha[r] = __expf(m_i[r] - mnew[r]);
      m_i[r] = mnew[r];
      rsum[r] = 0.f;
    }
#pragma unroll
    for (int nt = 0; nt < 4; ++nt)
#pragma unroll
      for (int r = 0; r < 4; ++r) {
        const float pv = __expf(sc[nt][r] - mnew[r]);
        const u16 pb = f2bf(pv);
        P[wave][(Lq * 4 + r) * PST + nt * 16 + L15] = pb;
        rsum[r] += bf2f(pb);
      }
#pragma unroll
    for (int r = 0; r < 4; ++r) {
      rsum[r] += __shfl_xor(rsum[r], 1);
      rsum[r] += __shfl_xor(rsum[r], 2);
      rsum[r] += __shfl_xor(rsum[r], 4);
      rsum[r] += __shfl_xor(rsum[r], 8);
      l_i[r] = l_i[r] * alpha[r] + rsum[r];
    }
    // per-wave P slice: C-layout -> A-layout, intra-wave lgkmcnt ordering suffices
    bf16x8 pa[2];
#pragma unroll
    for (int kc = 0; kc < 2; ++kc)
      pa[kc] = *(const bf16x8*)&P[wave][L15 * PST + kc * 32 + Lq * 8];
#pragma unroll
    for (int dt = 0; dt < 8; ++dt)
#pragma unroll
      for (int r = 0; r < 4; ++r) acc[dt][r] *= alpha[r];
    // ---- PV from LDS ----
#pragma unroll
    for (int dt = 0; dt < 8; ++dt)
#pragma unroll
      for (int kc = 0; kc < 2; ++kc) {
        const bf16x8 vf = *(const bf16x8*)&Vs[(dt * 16 + L15) * VST + kc * 32 + Lq * 8];
        acc[dt] = __builtin_amdgcn_mfma_f32_16x16x32_bf16(pa[kc], vf, acc[dt], 0, 0, 0);
      }
    __syncthreads();  // all waves done reading tile kt
    if (kt < qt) {
#pragma unroll
      for (int j = 0; j < 4; ++j) {
        *(bf16x8*)&Ks[(kr0 + j * 16) * KST + kc0] = kpre[j];
        *(bf16x8*)&Vs[(vr0 + j * 32) * VST + vc0] = vpre[j];
      }
      __syncthreads();  // tile kt+1 visible to all waves
    }
  }
  float inv[4];
#pragma unroll
  for (int r = 0; r < 4; ++r) inv[r] = 1.f / l_i[r];
  u16* cp = ctx + ((size_t)b * S_ + q0 + wave * 16) * (NH * HD) + h * HD;
#pragma unroll
  for (int dt = 0; dt < 8; ++dt)
#pragma unroll
    for (int r = 0; r < 4; ++r)
      cp[(size_t)(Lq * 4 + r) * (NH * HD) + dt * 16 + L15] = f2bf(acc[dt][r] * inv[r]);
}

extern "C" void kernel_launch(void* const* d_in, const int* in_sizes, int n_in,
                              void* d_out, int out_size, void* d_ws, size_t ws_size,
                              hipStream_t stream) {
  const float* x     = (const float*)d_in[0];
  const float* W_in  = (const float*)d_in[1];
  const float* b_in  = (const float*)d_in[2];
  const float* cw    = (const float*)d_in[3];
  const float* cb    = (const float*)d_in[4];
  const float* W_out = (const float*)d_in[5];
  const float* b_out = (const float*)d_in[6];

  char* ws = (char*)d_ws;
  u16* xb   = (u16*)(ws);                    // 16777216 B (dead after gemm1)
  u16* wib  = (u16*)(ws + 16777216);         // 12582912 B
  u16* wob  = (u16*)(ws + 29360128);         //  8388608 B
  u16* qkv  = (u16*)(ws + 37748736);         // 25165824 B
  u16* q_ws = (u16*)(ws + 62914560);         // 16777216 B
  u16* k_ws = (u16*)(ws + 79691776);         //  4194304 B
  u16* vt_ws= (u16*)(ws + 83886080);         //  4194304 B
  // rope tables live in the dead xb region (written after gemm1, dead before attn)
  float* ctab = (float*)ws;                  //  524288 B
  float* stab = (float*)(ws + 524288);       //  524288 B
  u16* ctx  = xb;                            // alias: xb dead after gemm1

  const int nx = B_ * S_ * E_ / 4, nwi = QKV_ * E_ / 4, nwo = E_ * NH * HD / 4;
  f2b_conv<<<dim3((nx  + 255) / 256), 256, 0, stream>>>(x,     xb,  nx);
  f2b_conv<<<dim3((nwi + 255) / 256), 256, 0, stream>>>(W_in,  wib, nwi);
  f2b_conv<<<dim3((nwo + 255) / 256), 256, 0, stream>>>(W_out, wob, nwo);

  gemm_bt<1><<<dim3(QKV_ / 128, (B_ * S_) / 128), 256, 0, stream>>>(
      xb, wib, b_in, (void*)qkv, B_ * S_, QKV_, E_);
  rope_tab<<<dim3(S_ * 64 / 256), 256, 0, stream>>>(ctab, stab);
  conv_rope<<<dim3(B_ * S_), 256, 0, stream>>>(qkv, cw, cb, ctab, stab, q_ws, k_ws, vt_ws);
  attn<<<dim3(S_ / 64, B_ * NH), 256, 0, stream>>>(q_ws, k_ws, vt_ws, ctx);
  gemm_bt<0><<<dim3(E_ / 128, (B_ * S_) / 128), 256, 0, stream>>>(
      ctx, wob, b_out, d_out, B_ * S_, E_, NH * HD);
}